// Round 4
// baseline (1313.503 us; speedup 1.0000x reference)
//
#include <hip/hip_runtime.h>

#define TB 256
#define SCAN_TB 1024

// ---------------- index-width detection (int32 vs int64 src/dst) -------------
__global__ void detect_idx_kernel(const int* __restrict__ s32, const int* __restrict__ d32,
                                  int nE, int* __restrict__ flag) {
    __shared__ int nz;
    if (threadIdx.x == 0) nz = 0;
    __syncthreads();
    int n = nE < 2048 ? nE : 2048;
    int local = 0;
    for (int i = threadIdx.x; i < n; i += blockDim.x) {
        if (s32[2 * i + 1] != 0 || d32[2 * i + 1] != 0) local = 1;
    }
    if (local) atomicOr(&nz, 1);
    __syncthreads();
    if (threadIdx.x == 0) *flag = (nz == 0) ? 1 : 0;   // 1 => indices are int64
}

__device__ __forceinline__ int load_idx(const void* p, int e, int is64) {
    return is64 ? (int)((const long long*)p)[e] : ((const int*)p)[e];
}

// ---------------- CSR build --------------------------------------------------
__global__ void hist_kernel(const void* __restrict__ dst, const int* __restrict__ flag,
                            int* __restrict__ deg, int nE) {
    int t = blockIdx.x * blockDim.x + threadIdx.x;
    if (t >= nE) return;
    atomicAdd(&deg[load_idx(dst, t, *flag)], 1);
}

__global__ __launch_bounds__(SCAN_TB) void scan_kernel(const int* __restrict__ deg,
                                                       int* __restrict__ rowptr, int M) {
    __shared__ int sh[SCAN_TB];
    int tid = threadIdx.x;
    int C = (M + SCAN_TB - 1) / SCAN_TB;
    int lo = tid * C;
    int hi = lo + C < M ? lo + C : M;
    int sum = 0;
    for (int i = lo; i < hi; ++i) sum += deg[i];
    sh[tid] = sum;
    __syncthreads();
    for (int off = 1; off < SCAN_TB; off <<= 1) {
        int t = (tid >= off) ? sh[tid - off] : 0;
        __syncthreads();
        sh[tid] += t;
        __syncthreads();
    }
    int base = (tid == 0) ? 0 : sh[tid - 1];
    int run = base;
    for (int i = lo; i < hi; ++i) { rowptr[i] = run; run += deg[i]; }
    if (tid == SCAN_TB - 1) rowptr[M] = sh[SCAN_TB - 1];
}

__global__ void copy_cursor_kernel(const int* __restrict__ rowptr, int* __restrict__ cursor, int M) {
    int t = blockIdx.x * blockDim.x + threadIdx.x;
    if (t < M) cursor[t] = rowptr[t];
}

__global__ void fill_kernel(const void* __restrict__ src, const void* __restrict__ dst,
                            const int* __restrict__ flag,
                            int* __restrict__ cursor, int* __restrict__ col, int nE) {
    int t = blockIdx.x * blockDim.x + threadIdx.x;
    if (t >= nE) return;
    int is64 = *flag;
    int d = load_idx(dst, t, is64);
    int s = load_idx(src, t, is64);
    int pos = atomicAdd(&cursor[d], 1);
    col[pos] = s;
}

// ---------------- fused gather: out = relu?(sbuf + mean_nbr(x)) (+concat) ----
// one node per wave. lanes = C4 column-chunks x ES edge-slices.
// if sbuf == null: out = mean_nbr(x) only (layer-1 pre-aggregate).
template<int F>
__global__ __launch_bounds__(TB) void gather_fused_kernel(
        const float4* __restrict__ x4, const int* __restrict__ col,
        const int* __restrict__ rowptr,
        const float* __restrict__ sbuf, const float* __restrict__ hcopy,
        float* __restrict__ out, int M, int ldout, int doRelu) {
    constexpr int C4 = F / 4;      // float4 chunks per row: 16 (F=64) or 8 (F=32)
    constexpr int ES = 64 / C4;    // edge slices per wave: 4 or 8
    const int wave = threadIdx.x >> 6;
    const int lane = threadIdx.x & 63;
    const int node = blockIdx.x * (TB / 64) + wave;
    if (node >= M) return;
    const int c4 = lane & (C4 - 1);
    const int es = lane >> (F == 64 ? 4 : 3);

    const int s = rowptr[node], e = rowptr[node + 1];
    float ax = 0.f, ay = 0.f, az = 0.f, aw = 0.f;
    for (int j = s + es; j < e; j += ES) {
        int cs = col[j];
        float4 v = x4[(size_t)cs * C4 + c4];
        ax += v.x; ay += v.y; az += v.z; aw += v.w;
    }
    // butterfly-reduce across edge slices (lane bits >= log2(C4))
    #pragma unroll
    for (int d = C4; d < 64; d <<= 1) {
        ax += __shfl_xor(ax, d);
        ay += __shfl_xor(ay, d);
        az += __shfl_xor(az, d);
        aw += __shfl_xor(aw, d);
    }
    if (es == 0) {
        const float inv = 1.0f / fmaxf((float)(e - s), 1.0f);
        float4 v = make_float4(ax * inv, ay * inv, az * inv, aw * inv);
        if (sbuf) {
            float4 sv = *(const float4*)(sbuf + (size_t)node * F + 4 * c4);
            v.x += sv.x; v.y += sv.y; v.z += sv.z; v.w += sv.w;
        }
        if (doRelu) {
            v.x = fmaxf(v.x, 0.f); v.y = fmaxf(v.y, 0.f);
            v.z = fmaxf(v.z, 0.f); v.w = fmaxf(v.w, 0.f);
        }
        float* orow = out + (size_t)node * ldout;
        *(float4*)(orow + 4 * c4) = v;
        if (hcopy) {  // concat: out[node, F + c] = hcopy[node, c]
            float4 hv = *(const float4*)(hcopy + (size_t)node * F + 4 * c4);
            *(float4*)(orow + F + 4 * c4) = hv;
        }
    }
}

// ---------------- dual-OUTPUT GEMM: Y = A@Wn ; S = A@Ws + b ------------------
// 256 threads = 32 row-groups x 8 col-groups; 2 rows/thread -> 64 rows/block
template<int K, int N>
__global__ __launch_bounds__(TB) void gemm_dualout_kernel(
        const float* __restrict__ A, const float* __restrict__ Wn,
        const float* __restrict__ Ws, const float* __restrict__ bias,
        float* __restrict__ Y, float* __restrict__ S, int M) {
    constexpr int C = N / 8;
    constexpr int NC4 = C / 4;
    const int colg = threadIdx.x & 7;
    const int rowg = threadIdx.x >> 3;
    const int row0 = blockIdx.x * 64 + rowg * 2;
    if (row0 >= M) return;   // M even -> both rows in or out
    const int c0 = colg * C;

    float4 accY[2][NC4], accS[2][NC4];
    #pragma unroll
    for (int r = 0; r < 2; ++r)
        #pragma unroll
        for (int j = 0; j < NC4; ++j) {
            accY[r][j] = make_float4(0.f, 0.f, 0.f, 0.f);
            accS[r][j] = make_float4(0.f, 0.f, 0.f, 0.f);
        }

    const float* a = A + (size_t)row0 * K;
    for (int k = 0; k < K; k += 4) {
        float4 av[2];
        #pragma unroll
        for (int r = 0; r < 2; ++r)
            av[r] = *(const float4*)(a + (size_t)r * K + k);
        #pragma unroll
        for (int kk = 0; kk < 4; ++kk) {
            const float* wnr = Wn + (size_t)(k + kk) * N + c0;
            const float* wsr = Ws + (size_t)(k + kk) * N + c0;
            #pragma unroll
            for (int j = 0; j < NC4; ++j) {
                float4 wn = *(const float4*)(wnr + 4 * j);
                float4 ws = *(const float4*)(wsr + 4 * j);
                #pragma unroll
                for (int r = 0; r < 2; ++r) {
                    float a_rk = ((const float*)&av[r])[kk];
                    accY[r][j].x += a_rk * wn.x; accY[r][j].y += a_rk * wn.y;
                    accY[r][j].z += a_rk * wn.z; accY[r][j].w += a_rk * wn.w;
                    accS[r][j].x += a_rk * ws.x; accS[r][j].y += a_rk * ws.y;
                    accS[r][j].z += a_rk * ws.z; accS[r][j].w += a_rk * ws.w;
                }
            }
        }
    }

    #pragma unroll
    for (int j = 0; j < NC4; ++j) {
        const int c = c0 + 4 * j;
        float4 bb = *(const float4*)(bias + c);
        #pragma unroll
        for (int r = 0; r < 2; ++r) {
            const int row = row0 + r;
            *(float4*)(Y + (size_t)row * N + c) = accY[r][j];
            float4 v = accS[r][j];
            v.x += bb.x; v.y += bb.y; v.z += bb.z; v.w += bb.w;
            *(float4*)(S + (size_t)row * N + c) = v;
        }
    }
}

// ---------------- dual-INPUT GEMM (layer 1): out = relu(A@W + A2@W2 + b) -----
template<int K, int N>
__global__ __launch_bounds__(TB) void gemm_dualin_kernel(
        const float* __restrict__ A, const float* __restrict__ W,
        const float* __restrict__ A2, const float* __restrict__ W2,
        const float* __restrict__ bias, float* __restrict__ out, int M) {
    constexpr int C = N / 8;
    constexpr int NC4 = C / 4;
    const int colg = threadIdx.x & 7;
    const int rowg = threadIdx.x >> 3;
    const int row0 = blockIdx.x * 64 + rowg * 2;
    if (row0 >= M) return;
    const int c0 = colg * C;

    float4 acc[2][NC4];
    #pragma unroll
    for (int r = 0; r < 2; ++r)
        #pragma unroll
        for (int j = 0; j < NC4; ++j) acc[r][j] = make_float4(0.f, 0.f, 0.f, 0.f);

    const float* a = A + (size_t)row0 * K;
    const float* a2 = A2 + (size_t)row0 * K;
    for (int k = 0; k < K; k += 4) {
        float4 av[2], av2[2];
        #pragma unroll
        for (int r = 0; r < 2; ++r) {
            av[r]  = *(const float4*)(a  + (size_t)r * K + k);
            av2[r] = *(const float4*)(a2 + (size_t)r * K + k);
        }
        #pragma unroll
        for (int kk = 0; kk < 4; ++kk) {
            const float* wr  = W  + (size_t)(k + kk) * N + c0;
            const float* wr2 = W2 + (size_t)(k + kk) * N + c0;
            #pragma unroll
            for (int j = 0; j < NC4; ++j) {
                float4 wv  = *(const float4*)(wr + 4 * j);
                float4 wv2 = *(const float4*)(wr2 + 4 * j);
                #pragma unroll
                for (int r = 0; r < 2; ++r) {
                    float a_rk  = ((const float*)&av[r])[kk];
                    float a2_rk = ((const float*)&av2[r])[kk];
                    acc[r][j].x += a_rk * wv.x + a2_rk * wv2.x;
                    acc[r][j].y += a_rk * wv.y + a2_rk * wv2.y;
                    acc[r][j].z += a_rk * wv.z + a2_rk * wv2.z;
                    acc[r][j].w += a_rk * wv.w + a2_rk * wv2.w;
                }
            }
        }
    }

    #pragma unroll
    for (int j = 0; j < NC4; ++j) {
        const int c = c0 + 4 * j;
        float4 bb = *(const float4*)(bias + c);
        #pragma unroll
        for (int r = 0; r < 2; ++r) {
            float4 v = acc[r][j];
            v.x = fmaxf(v.x + bb.x, 0.f);
            v.y = fmaxf(v.y + bb.y, 0.f);
            v.z = fmaxf(v.z + bb.z, 0.f);
            v.w = fmaxf(v.w + bb.w, 0.f);
            *(float4*)(out + (size_t)(row0 + r) * N + c) = v;
        }
    }
}

// ---------------- host orchestration ----------------------------------------
static inline int cdiv_i(long long a, int b) { return (int)((a + b - 1) / b); }

template<int F>
static void launch_gather(const float* x, const int* col, const int* rowptr,
                          const float* sbuf, const float* hcopy,
                          float* out, int M, int ldout, int relu, hipStream_t stream) {
    hipLaunchKernelGGL((gather_fused_kernel<F>), dim3(cdiv_i(M, TB / 64)), dim3(TB), 0, stream,
                       (const float4*)x, col, rowptr, sbuf, hcopy, out, M, ldout, relu);
}

extern "C" void kernel_launch(void* const* d_in, const int* in_sizes, int n_in,
                              void* d_out, int out_size, void* d_ws, size_t ws_size,
                              hipStream_t stream) {
    const float* in_feat = (const float*)d_in[0];
    const void* src = d_in[1];
    const void* dst = d_in[2];
    const float* Ws1 = (const float*)d_in[3];  const float* Wn1 = (const float*)d_in[4];  const float* b1 = (const float*)d_in[5];
    const float* Ws2 = (const float*)d_in[6];  const float* Wn2 = (const float*)d_in[7];  const float* b2 = (const float*)d_in[8];
    const float* Ws3 = (const float*)d_in[9];  const float* Wn3 = (const float*)d_in[10]; const float* b3 = (const float*)d_in[11];
    const float* Ws4 = (const float*)d_in[12]; const float* Wn4 = (const float*)d_in[13]; const float* b4 = (const float*)d_in[14];
    const float* Ws5 = (const float*)d_in[15]; const float* Wn5 = (const float*)d_in[16]; const float* b5 = (const float*)d_in[17];
    const float* Ws6 = (const float*)d_in[18]; const float* Wn6 = (const float*)d_in[19]; const float* b6 = (const float*)d_in[20];

    const int M  = in_sizes[0] / 64;   // 100000 nodes
    const int nE = in_sizes[1];        // 1600000 edges

    // workspace layout (same footprint as round 3)
    float* ws   = (float*)d_ws;
    float* P1   = ws;                        // M*128  (h1, later h5)
    float* P2   = P1 + (size_t)M * 128;      // M*64   (h2, later h4)
    float* P3   = P2 + (size_t)M * 64;       // M*32   (h3)
    float* ybuf = P3 + (size_t)M * 32;       // M*64   (transformed features to aggregate)
    float* sbuf = ybuf + (size_t)M * 64;     // M*64   (self part + bias)
    int* deg    = (int*)(sbuf + (size_t)M * 64);  // M ints (later cursor)
    int* rowptr = deg + M;                   // M+1 ints
    int* col    = rowptr + (M + 1);          // nE ints
    int* flag   = col + nE;                  // 1 int

    // ---- CSR build
    hipLaunchKernelGGL(detect_idx_kernel, dim3(1), dim3(TB), 0, stream,
                       (const int*)src, (const int*)dst, nE, flag);
    hipMemsetAsync(deg, 0, (size_t)M * sizeof(int), stream);
    hipLaunchKernelGGL(hist_kernel, dim3(cdiv_i(nE, TB)), dim3(TB), 0, stream,
                       dst, flag, deg, nE);
    hipLaunchKernelGGL(scan_kernel, dim3(1), dim3(SCAN_TB), 0, stream, deg, rowptr, M);
    hipLaunchKernelGGL(copy_cursor_kernel, dim3(cdiv_i(M, TB)), dim3(TB), 0, stream,
                       rowptr, deg, M);  // deg becomes cursor
    hipLaunchKernelGGL(fill_kernel, dim3(cdiv_i(nE, TB)), dim3(TB), 0, stream,
                       src, dst, flag, deg, col, nE);

    // ---- layer 1: 64 -> 128, relu.  ybuf = mean_nbr(in_feat); dual-input GEMM
    launch_gather<64>(in_feat, col, rowptr, nullptr, nullptr, ybuf, M, 64, 0, stream);
    hipLaunchKernelGGL((gemm_dualin_kernel<64, 128>), dim3(cdiv_i(M, 64)), dim3(TB), 0, stream,
                       in_feat, Ws1, ybuf, Wn1, b1, P1, M);

    // ---- layer 2: 128 -> 64, relu
    hipLaunchKernelGGL((gemm_dualout_kernel<128, 64>), dim3(cdiv_i(M, 64)), dim3(TB), 0, stream,
                       P1, Wn2, Ws2, b2, ybuf, sbuf, M);
    launch_gather<64>(ybuf, col, rowptr, sbuf, nullptr, P2, M, 64, 1, stream);

    // ---- layer 3: 64 -> 32, relu
    hipLaunchKernelGGL((gemm_dualout_kernel<64, 32>), dim3(cdiv_i(M, 64)), dim3(TB), 0, stream,
                       P2, Wn3, Ws3, b3, ybuf, sbuf, M);
    launch_gather<32>(ybuf, col, rowptr, sbuf, nullptr, P3, M, 32, 1, stream);

    // ---- layer 4: 32 -> 32, relu, concat h3 -> h4 (64 wide) in P2
    hipLaunchKernelGGL((gemm_dualout_kernel<32, 32>), dim3(cdiv_i(M, 64)), dim3(TB), 0, stream,
                       P3, Wn4, Ws4, b4, ybuf, sbuf, M);
    launch_gather<32>(ybuf, col, rowptr, sbuf, P3, P2, M, 64, 1, stream);

    // ---- layer 5: 64 -> 64, relu, concat h4 -> h5 (128 wide) in P1
    hipLaunchKernelGGL((gemm_dualout_kernel<64, 64>), dim3(cdiv_i(M, 64)), dim3(TB), 0, stream,
                       P2, Wn5, Ws5, b5, ybuf, sbuf, M);
    launch_gather<64>(ybuf, col, rowptr, sbuf, P2, P1, M, 128, 1, stream);

    // ---- layer 6: 128 -> 64, no relu, to d_out
    hipLaunchKernelGGL((gemm_dualout_kernel<128, 64>), dim3(cdiv_i(M, 64)), dim3(TB), 0, stream,
                       P1, Wn6, Ws6, b6, ybuf, sbuf, M);
    launch_gather<64>(ybuf, col, rowptr, sbuf, nullptr, (float*)d_out, M, 64, 0, stream);
}

// Round 5
// 959.237 us; speedup vs baseline: 1.3693x; 1.3693x over previous
//
#include <hip/hip_runtime.h>

#define TB 256
#define SCAN_TB 1024

// ---------------- index-width detection (int32 vs int64 src/dst) -------------
__global__ void detect_idx_kernel(const int* __restrict__ s32, const int* __restrict__ d32,
                                  int nE, int* __restrict__ flag) {
    __shared__ int nz;
    if (threadIdx.x == 0) nz = 0;
    __syncthreads();
    int n = nE < 2048 ? nE : 2048;
    int local = 0;
    for (int i = threadIdx.x; i < n; i += blockDim.x) {
        if (s32[2 * i + 1] != 0 || d32[2 * i + 1] != 0) local = 1;
    }
    if (local) atomicOr(&nz, 1);
    __syncthreads();
    if (threadIdx.x == 0) *flag = (nz == 0) ? 1 : 0;   // 1 => indices are int64
}

__device__ __forceinline__ int load_idx(const void* p, int e, int is64) {
    return is64 ? (int)((const long long*)p)[e] : ((const int*)p)[e];
}

// ---------------- CSR build --------------------------------------------------
__global__ void hist_kernel(const void* __restrict__ dst, const int* __restrict__ flag,
                            int* __restrict__ deg, int nE) {
    int t = blockIdx.x * blockDim.x + threadIdx.x;
    if (t >= nE) return;
    atomicAdd(&deg[load_idx(dst, t, *flag)], 1);
}

__global__ __launch_bounds__(SCAN_TB) void scan_kernel(const int* __restrict__ deg,
                                                       int* __restrict__ rowptr, int M) {
    __shared__ int sh[SCAN_TB];
    int tid = threadIdx.x;
    int C = (M + SCAN_TB - 1) / SCAN_TB;
    int lo = tid * C;
    int hi = lo + C < M ? lo + C : M;
    int sum = 0;
    for (int i = lo; i < hi; ++i) sum += deg[i];
    sh[tid] = sum;
    __syncthreads();
    for (int off = 1; off < SCAN_TB; off <<= 1) {
        int t = (tid >= off) ? sh[tid - off] : 0;
        __syncthreads();
        sh[tid] += t;
        __syncthreads();
    }
    int base = (tid == 0) ? 0 : sh[tid - 1];
    int run = base;
    for (int i = lo; i < hi; ++i) { rowptr[i] = run; run += deg[i]; }
    if (tid == SCAN_TB - 1) rowptr[M] = sh[SCAN_TB - 1];
}

__global__ void copy_cursor_kernel(const int* __restrict__ rowptr, int* __restrict__ cursor, int M) {
    int t = blockIdx.x * blockDim.x + threadIdx.x;
    if (t < M) cursor[t] = rowptr[t];
}

__global__ void fill_kernel(const void* __restrict__ src, const void* __restrict__ dst,
                            const int* __restrict__ flag,
                            int* __restrict__ cursor, int* __restrict__ col, int nE) {
    int t = blockIdx.x * blockDim.x + threadIdx.x;
    if (t >= nE) return;
    int is64 = *flag;
    int d = load_idx(dst, t, is64);
    int s = load_idx(src, t, is64);
    int pos = atomicAdd(&cursor[d], 1);
    col[pos] = s;
}

// ---------------- fused gather: out = relu?(sbuf + mean_nbr(x)) (+concat) ----
template<int F>
__global__ __launch_bounds__(TB) void gather_fused_kernel(
        const float4* __restrict__ x4, const int* __restrict__ col,
        const int* __restrict__ rowptr,
        const float* __restrict__ sbuf, const float* __restrict__ hcopy,
        float* __restrict__ out, int M, int ldout, int doRelu) {
    constexpr int C4 = F / 4;      // float4 chunks per row: 16 (F=64) or 8 (F=32)
    constexpr int ES = 64 / C4;    // edge slices per wave
    const int wave = threadIdx.x >> 6;
    const int lane = threadIdx.x & 63;
    const int node = blockIdx.x * (TB / 64) + wave;
    if (node >= M) return;
    const int c4 = lane & (C4 - 1);
    const int es = lane >> (F == 64 ? 4 : 3);

    const int s = rowptr[node], e = rowptr[node + 1];
    float ax = 0.f, ay = 0.f, az = 0.f, aw = 0.f;
    for (int j = s + es; j < e; j += ES) {
        int cs = col[j];
        float4 v = x4[(size_t)cs * C4 + c4];
        ax += v.x; ay += v.y; az += v.z; aw += v.w;
    }
    #pragma unroll
    for (int d = C4; d < 64; d <<= 1) {
        ax += __shfl_xor(ax, d);
        ay += __shfl_xor(ay, d);
        az += __shfl_xor(az, d);
        aw += __shfl_xor(aw, d);
    }
    if (es == 0) {
        const float inv = 1.0f / fmaxf((float)(e - s), 1.0f);
        float4 v = make_float4(ax * inv, ay * inv, az * inv, aw * inv);
        if (sbuf) {
            float4 sv = *(const float4*)(sbuf + (size_t)node * F + 4 * c4);
            v.x += sv.x; v.y += sv.y; v.z += sv.z; v.w += sv.w;
        }
        if (doRelu) {
            v.x = fmaxf(v.x, 0.f); v.y = fmaxf(v.y, 0.f);
            v.z = fmaxf(v.z, 0.f); v.w = fmaxf(v.w, 0.f);
        }
        float* orow = out + (size_t)node * ldout;
        *(float4*)(orow + 4 * c4) = v;
        if (hcopy) {
            float4 hv = *(const float4*)(hcopy + (size_t)node * F + 4 * c4);
            *(float4*)(orow + F + 4 * c4) = hv;
        }
    }
}

// ---------------- LDS-staged dual-OUTPUT GEMM: Y = A@Wn ; S = A@Ws + b -------
// 256 threads = 32 rowgroups x 8 colgroups, 2 rows/thread -> 64 rows/block.
// W chunks (KC k-rows of both matrices, 16 KB) staged in LDS.
template<int K, int N>
__global__ __launch_bounds__(TB) void gemm_dualout_lds(
        const float* __restrict__ A, const float* __restrict__ Wn,
        const float* __restrict__ Ws, const float* __restrict__ bias,
        float* __restrict__ Y, float* __restrict__ S, int M) {
    constexpr int C = N / 8;              // cols per thread
    constexpr int NC4 = C / 4;            // float4s per thread
    constexpr int KC0 = 2048 / N;         // chunk k-rows for 16 KB total
    constexpr int KC = KC0 < K ? KC0 : K;
    constexpr int P4 = (KC * N) / 1024;   // staging float4s per thread per matrix

    __shared__ float lwn[KC * N];
    __shared__ float lws[KC * N];

    const int tid = threadIdx.x;
    const int colg = tid & 7;
    const int rowg = tid >> 3;
    const int row0 = blockIdx.x * 64 + rowg * 2;
    const bool valid = row0 < M;          // M even -> both rows in or out
    const int c0 = colg * C;

    float4 accY[2][NC4], accS[2][NC4];
    #pragma unroll
    for (int r = 0; r < 2; ++r)
        #pragma unroll
        for (int j = 0; j < NC4; ++j) {
            accY[r][j] = make_float4(0.f, 0.f, 0.f, 0.f);
            accS[r][j] = make_float4(0.f, 0.f, 0.f, 0.f);
        }

    for (int kc = 0; kc < K; kc += KC) {
        __syncthreads();
        const float4* gwn = (const float4*)(Wn + (size_t)kc * N);
        const float4* gws = (const float4*)(Ws + (size_t)kc * N);
        #pragma unroll
        for (int i = 0; i < P4; ++i) {
            int f4i = tid + i * 256;
            ((float4*)lwn)[f4i] = gwn[f4i];
            ((float4*)lws)[f4i] = gws[f4i];
        }
        __syncthreads();
        if (valid) {
            const float* a = A + (size_t)row0 * K + kc;
            for (int k = 0; k < KC; k += 4) {
                float4 av[2];
                #pragma unroll
                for (int r = 0; r < 2; ++r)
                    av[r] = *(const float4*)(a + (size_t)r * K + k);
                #pragma unroll
                for (int kk = 0; kk < 4; ++kk) {
                    #pragma unroll
                    for (int j = 0; j < NC4; ++j) {
                        float4 wn = *(const float4*)(&lwn[(k + kk) * N + c0 + 4 * j]);
                        float4 ws = *(const float4*)(&lws[(k + kk) * N + c0 + 4 * j]);
                        #pragma unroll
                        for (int r = 0; r < 2; ++r) {
                            float ar = ((const float*)&av[r])[kk];
                            accY[r][j].x += ar * wn.x; accY[r][j].y += ar * wn.y;
                            accY[r][j].z += ar * wn.z; accY[r][j].w += ar * wn.w;
                            accS[r][j].x += ar * ws.x; accS[r][j].y += ar * ws.y;
                            accS[r][j].z += ar * ws.z; accS[r][j].w += ar * ws.w;
                        }
                    }
                }
            }
        }
    }

    if (valid) {
        #pragma unroll
        for (int j = 0; j < NC4; ++j) {
            const int c = c0 + 4 * j;
            float4 bb = *(const float4*)(bias + c);
            #pragma unroll
            for (int r = 0; r < 2; ++r) {
                const int row = row0 + r;
                *(float4*)(Y + (size_t)row * N + c) = accY[r][j];
                float4 v = accS[r][j];
                v.x += bb.x; v.y += bb.y; v.z += bb.z; v.w += bb.w;
                *(float4*)(S + (size_t)row * N + c) = v;
            }
        }
    }
}

// ---------------- LDS-staged dual-INPUT GEMM: out = relu(A@W + A2@W2 + b) ----
template<int K, int N>
__global__ __launch_bounds__(TB) void gemm_dualin_lds(
        const float* __restrict__ A, const float* __restrict__ W,
        const float* __restrict__ A2, const float* __restrict__ W2,
        const float* __restrict__ bias, float* __restrict__ out, int M) {
    constexpr int C = N / 8;
    constexpr int NC4 = C / 4;
    constexpr int KC0 = 2048 / N;
    constexpr int KC = KC0 < K ? KC0 : K;
    constexpr int P4 = (KC * N) / 1024;

    __shared__ float lw[KC * N];
    __shared__ float lw2[KC * N];

    const int tid = threadIdx.x;
    const int colg = tid & 7;
    const int rowg = tid >> 3;
    const int row0 = blockIdx.x * 64 + rowg * 2;
    const bool valid = row0 < M;
    const int c0 = colg * C;

    float4 acc[2][NC4];
    #pragma unroll
    for (int r = 0; r < 2; ++r)
        #pragma unroll
        for (int j = 0; j < NC4; ++j) acc[r][j] = make_float4(0.f, 0.f, 0.f, 0.f);

    for (int kc = 0; kc < K; kc += KC) {
        __syncthreads();
        const float4* gw  = (const float4*)(W  + (size_t)kc * N);
        const float4* gw2 = (const float4*)(W2 + (size_t)kc * N);
        #pragma unroll
        for (int i = 0; i < P4; ++i) {
            int f4i = tid + i * 256;
            ((float4*)lw)[f4i]  = gw[f4i];
            ((float4*)lw2)[f4i] = gw2[f4i];
        }
        __syncthreads();
        if (valid) {
            const float* a  = A  + (size_t)row0 * K + kc;
            const float* a2 = A2 + (size_t)row0 * K + kc;
            for (int k = 0; k < KC; k += 4) {
                float4 av[2], av2[2];
                #pragma unroll
                for (int r = 0; r < 2; ++r) {
                    av[r]  = *(const float4*)(a  + (size_t)r * K + k);
                    av2[r] = *(const float4*)(a2 + (size_t)r * K + k);
                }
                #pragma unroll
                for (int kk = 0; kk < 4; ++kk) {
                    #pragma unroll
                    for (int j = 0; j < NC4; ++j) {
                        float4 wv  = *(const float4*)(&lw[(k + kk) * N + c0 + 4 * j]);
                        float4 wv2 = *(const float4*)(&lw2[(k + kk) * N + c0 + 4 * j]);
                        #pragma unroll
                        for (int r = 0; r < 2; ++r) {
                            float ar  = ((const float*)&av[r])[kk];
                            float ar2 = ((const float*)&av2[r])[kk];
                            acc[r][j].x += ar * wv.x + ar2 * wv2.x;
                            acc[r][j].y += ar * wv.y + ar2 * wv2.y;
                            acc[r][j].z += ar * wv.z + ar2 * wv2.z;
                            acc[r][j].w += ar * wv.w + ar2 * wv2.w;
                        }
                    }
                }
            }
        }
    }

    if (valid) {
        #pragma unroll
        for (int j = 0; j < NC4; ++j) {
            const int c = c0 + 4 * j;
            float4 bb = *(const float4*)(bias + c);
            #pragma unroll
            for (int r = 0; r < 2; ++r) {
                float4 v = acc[r][j];
                v.x = fmaxf(v.x + bb.x, 0.f);
                v.y = fmaxf(v.y + bb.y, 0.f);
                v.z = fmaxf(v.z + bb.z, 0.f);
                v.w = fmaxf(v.w + bb.w, 0.f);
                *(float4*)(out + (size_t)(row0 + r) * N + c) = v;
            }
        }
    }
}

// ---------------- host orchestration ----------------------------------------
static inline int cdiv_i(long long a, int b) { return (int)((a + b - 1) / b); }

template<int F>
static void launch_gather(const float* x, const int* col, const int* rowptr,
                          const float* sbuf, const float* hcopy,
                          float* out, int M, int ldout, int relu, hipStream_t stream) {
    hipLaunchKernelGGL((gather_fused_kernel<F>), dim3(cdiv_i(M, TB / 64)), dim3(TB), 0, stream,
                       (const float4*)x, col, rowptr, sbuf, hcopy, out, M, ldout, relu);
}

extern "C" void kernel_launch(void* const* d_in, const int* in_sizes, int n_in,
                              void* d_out, int out_size, void* d_ws, size_t ws_size,
                              hipStream_t stream) {
    const float* in_feat = (const float*)d_in[0];
    const void* src = d_in[1];
    const void* dst = d_in[2];
    const float* Ws1 = (const float*)d_in[3];  const float* Wn1 = (const float*)d_in[4];  const float* b1 = (const float*)d_in[5];
    const float* Ws2 = (const float*)d_in[6];  const float* Wn2 = (const float*)d_in[7];  const float* b2 = (const float*)d_in[8];
    const float* Ws3 = (const float*)d_in[9];  const float* Wn3 = (const float*)d_in[10]; const float* b3 = (const float*)d_in[11];
    const float* Ws4 = (const float*)d_in[12]; const float* Wn4 = (const float*)d_in[13]; const float* b4 = (const float*)d_in[14];
    const float* Ws5 = (const float*)d_in[15]; const float* Wn5 = (const float*)d_in[16]; const float* b5 = (const float*)d_in[17];
    const float* Ws6 = (const float*)d_in[18]; const float* Wn6 = (const float*)d_in[19]; const float* b6 = (const float*)d_in[20];

    const int M  = in_sizes[0] / 64;   // 100000 nodes
    const int nE = in_sizes[1];        // 1600000 edges

    // workspace layout
    float* ws   = (float*)d_ws;
    float* P1   = ws;                        // M*128  (h1, later h5)
    float* P2   = P1 + (size_t)M * 128;      // M*64   (h2, later h4)
    float* P3   = P2 + (size_t)M * 64;       // M*32   (h3)
    float* ybuf = P3 + (size_t)M * 32;       // M*64   (transformed features to aggregate)
    float* sbuf = ybuf + (size_t)M * 64;     // M*64   (self part + bias)
    int* deg    = (int*)(sbuf + (size_t)M * 64);  // M ints (later cursor)
    int* rowptr = deg + M;                   // M+1 ints
    int* col    = rowptr + (M + 1);          // nE ints
    int* flag   = col + nE;                  // 1 int

    // ---- CSR build
    hipLaunchKernelGGL(detect_idx_kernel, dim3(1), dim3(TB), 0, stream,
                       (const int*)src, (const int*)dst, nE, flag);
    hipMemsetAsync(deg, 0, (size_t)M * sizeof(int), stream);
    hipLaunchKernelGGL(hist_kernel, dim3(cdiv_i(nE, TB)), dim3(TB), 0, stream,
                       dst, flag, deg, nE);
    hipLaunchKernelGGL(scan_kernel, dim3(1), dim3(SCAN_TB), 0, stream, deg, rowptr, M);
    hipLaunchKernelGGL(copy_cursor_kernel, dim3(cdiv_i(M, TB)), dim3(TB), 0, stream,
                       rowptr, deg, M);  // deg becomes cursor
    hipLaunchKernelGGL(fill_kernel, dim3(cdiv_i(nE, TB)), dim3(TB), 0, stream,
                       src, dst, flag, deg, col, nE);

    const int gblocks = cdiv_i(M, 64);

    // ---- layer 1: 64 -> 128, relu.  ybuf = mean_nbr(in_feat); dual-input GEMM
    launch_gather<64>(in_feat, col, rowptr, nullptr, nullptr, ybuf, M, 64, 0, stream);
    hipLaunchKernelGGL((gemm_dualin_lds<64, 128>), dim3(gblocks), dim3(TB), 0, stream,
                       in_feat, Ws1, ybuf, Wn1, b1, P1, M);

    // ---- layer 2: 128 -> 64, relu
    hipLaunchKernelGGL((gemm_dualout_lds<128, 64>), dim3(gblocks), dim3(TB), 0, stream,
                       P1, Wn2, Ws2, b2, ybuf, sbuf, M);
    launch_gather<64>(ybuf, col, rowptr, sbuf, nullptr, P2, M, 64, 1, stream);

    // ---- layer 3: 64 -> 32, relu
    hipLaunchKernelGGL((gemm_dualout_lds<64, 32>), dim3(gblocks), dim3(TB), 0, stream,
                       P2, Wn3, Ws3, b3, ybuf, sbuf, M);
    launch_gather<32>(ybuf, col, rowptr, sbuf, nullptr, P3, M, 32, 1, stream);

    // ---- layer 4: 32 -> 32, relu, concat h3 -> h4 (64 wide) in P2
    hipLaunchKernelGGL((gemm_dualout_lds<32, 32>), dim3(gblocks), dim3(TB), 0, stream,
                       P3, Wn4, Ws4, b4, ybuf, sbuf, M);
    launch_gather<32>(ybuf, col, rowptr, sbuf, P3, P2, M, 64, 1, stream);

    // ---- layer 5: 64 -> 64, relu, concat h4 -> h5 (128 wide) in P1
    hipLaunchKernelGGL((gemm_dualout_lds<64, 64>), dim3(gblocks), dim3(TB), 0, stream,
                       P2, Wn5, Ws5, b5, ybuf, sbuf, M);
    launch_gather<64>(ybuf, col, rowptr, sbuf, P2, P1, M, 128, 1, stream);

    // ---- layer 6: 128 -> 64, no relu, to d_out
    hipLaunchKernelGGL((gemm_dualout_lds<128, 64>), dim3(gblocks), dim3(TB), 0, stream,
                       P1, Wn6, Ws6, b6, ybuf, sbuf, M);
    launch_gather<64>(ybuf, col, rowptr, sbuf, nullptr, (float*)d_out, M, 64, 0, stream);
}

// Round 6
// 778.242 us; speedup vs baseline: 1.6878x; 1.2326x over previous
//
#include <hip/hip_runtime.h>

#define TB 256
#define CHUNK 2048

// ---------------- index-width detection (int32 vs int64 src/dst) -------------
__global__ void detect_idx_kernel(const int* __restrict__ s32, const int* __restrict__ d32,
                                  int nE, int* __restrict__ flag) {
    __shared__ int nz;
    if (threadIdx.x == 0) nz = 0;
    __syncthreads();
    int n = nE < 2048 ? nE : 2048;
    int local = 0;
    for (int i = threadIdx.x; i < n; i += blockDim.x) {
        if (s32[2 * i + 1] != 0 || d32[2 * i + 1] != 0) local = 1;
    }
    if (local) atomicOr(&nz, 1);
    __syncthreads();
    if (threadIdx.x == 0) *flag = (nz == 0) ? 1 : 0;   // 1 => indices are int64
}

__device__ __forceinline__ int load_idx(const void* p, int e, int is64) {
    return is64 ? (int)((const long long*)p)[e] : ((const int*)p)[e];
}

// ---------------- CSR build --------------------------------------------------
__global__ void hist_kernel(const void* __restrict__ dst, const int* __restrict__ flag,
                            int* __restrict__ deg, int nE) {
    int t = blockIdx.x * blockDim.x + threadIdx.x;
    if (t >= nE) return;
    atomicAdd(&deg[load_idx(dst, t, *flag)], 1);
}

// stage A: per-chunk sums (CHUNK=2048 elems per 256-thread block, 8/thread)
__global__ __launch_bounds__(TB) void bsum_kernel(const int* __restrict__ deg,
                                                  int* __restrict__ bsum, int M) {
    const int tid = threadIdx.x;
    const int base = blockIdx.x * CHUNK + tid * 8;
    int s = 0;
    if (base + 8 <= M) {
        int4 a = *(const int4*)(deg + base);
        int4 c = *(const int4*)(deg + base + 4);
        s = a.x + a.y + a.z + a.w + c.x + c.y + c.z + c.w;
    } else {
        for (int i = 0; i < 8; ++i) if (base + i < M) s += deg[base + i];
    }
    #pragma unroll
    for (int off = 1; off < 64; off <<= 1) s += __shfl_xor(s, off);
    __shared__ int wsum[4];
    const int lane = tid & 63, wv = tid >> 6;
    if (lane == 0) wsum[wv] = s;
    __syncthreads();
    if (tid == 0) bsum[blockIdx.x] = wsum[0] + wsum[1] + wsum[2] + wsum[3];
}

// stage B: one wave exclusive-scans chunk sums (nB <= 64), writes rowptr[M]
__global__ void topscan_kernel(const int* __restrict__ bsum, int* __restrict__ boff,
                               int* __restrict__ rowptr, int nB, int M) {
    const int tid = threadIdx.x;   // 64 threads
    int v = (tid < nB) ? bsum[tid] : 0;
    int x = v;
    #pragma unroll
    for (int off = 1; off < 64; off <<= 1) {
        int y = __shfl_up(x, off);
        if (tid >= off) x += y;
    }
    if (tid < nB) boff[tid] = x - v;   // exclusive
    if (tid == 63) rowptr[M] = x;      // grand total
}

// stage C: chunk-local exclusive scan + chunk offset -> rowptr and cursor
__global__ __launch_bounds__(TB) void scan_chunk_kernel(
        const int* __restrict__ deg, const int* __restrict__ boff,
        int* __restrict__ rowptr, int* __restrict__ cursor, int M) {
    const int tid = threadIdx.x;
    const int base = blockIdx.x * CHUNK + tid * 8;
    int v[8];
    if (base + 8 <= M) {
        int4 a = *(const int4*)(deg + base);
        int4 c = *(const int4*)(deg + base + 4);
        v[0] = a.x; v[1] = a.y; v[2] = a.z; v[3] = a.w;
        v[4] = c.x; v[5] = c.y; v[6] = c.z; v[7] = c.w;
    } else {
        #pragma unroll
        for (int i = 0; i < 8; ++i) v[i] = (base + i < M) ? deg[base + i] : 0;
    }
    int tsum = 0;
    #pragma unroll
    for (int i = 0; i < 8; ++i) tsum += v[i];
    const int lane = tid & 63, wv = tid >> 6;
    int x = tsum;
    #pragma unroll
    for (int off = 1; off < 64; off <<= 1) {
        int y = __shfl_up(x, off);
        if (lane >= off) x += y;
    }
    __shared__ int wsum[4];
    if (lane == 63) wsum[wv] = x;
    __syncthreads();
    int wbase = 0;
    #pragma unroll
    for (int w = 0; w < 4; ++w) if (w < wv) wbase += wsum[w];
    int run = boff[blockIdx.x] + wbase + (x - tsum);   // thread's exclusive prefix
    #pragma unroll
    for (int i = 0; i < 8; ++i) {
        int idx = base + i;
        if (idx < M) { rowptr[idx] = run; cursor[idx] = run; }
        run += v[i];
    }
}

__global__ void fill_kernel(const void* __restrict__ src, const void* __restrict__ dst,
                            const int* __restrict__ flag,
                            int* __restrict__ cursor, int* __restrict__ col, int nE) {
    int t = blockIdx.x * blockDim.x + threadIdx.x;
    if (t >= nE) return;
    int is64 = *flag;
    int d = load_idx(dst, t, is64);
    int s = load_idx(src, t, is64);
    int pos = atomicAdd(&cursor[d], 1);
    col[pos] = s;
}

// ---------------- fused gather: out = relu?(sbuf + mean_nbr(x)) (+concat) ----
template<int F>
__global__ __launch_bounds__(TB) void gather_fused_kernel(
        const float4* __restrict__ x4, const int* __restrict__ col,
        const int* __restrict__ rowptr,
        const float* __restrict__ sbuf, const float* __restrict__ hcopy,
        float* __restrict__ out, int M, int ldout, int doRelu) {
    constexpr int C4 = F / 4;      // float4 chunks per row: 16 (F=64) or 8 (F=32)
    constexpr int ES = 64 / C4;    // edge slices per wave
    const int wave = threadIdx.x >> 6;
    const int lane = threadIdx.x & 63;
    const int node = blockIdx.x * (TB / 64) + wave;
    if (node >= M) return;
    const int c4 = lane & (C4 - 1);
    const int es = lane >> (F == 64 ? 4 : 3);

    const int s = rowptr[node], e = rowptr[node + 1];
    float ax = 0.f, ay = 0.f, az = 0.f, aw = 0.f;
    int j = s + es;
    // 2-deep software pipeline: two index+feature loads in flight
    for (; j + ES < e; j += 2 * ES) {
        int cs0 = col[j];
        int cs1 = col[j + ES];
        float4 v0 = x4[(size_t)cs0 * C4 + c4];
        float4 v1 = x4[(size_t)cs1 * C4 + c4];
        ax += v0.x + v1.x; ay += v0.y + v1.y;
        az += v0.z + v1.z; aw += v0.w + v1.w;
    }
    if (j < e) {
        int cs = col[j];
        float4 v = x4[(size_t)cs * C4 + c4];
        ax += v.x; ay += v.y; az += v.z; aw += v.w;
    }
    #pragma unroll
    for (int d = C4; d < 64; d <<= 1) {
        ax += __shfl_xor(ax, d);
        ay += __shfl_xor(ay, d);
        az += __shfl_xor(az, d);
        aw += __shfl_xor(aw, d);
    }
    if (es == 0) {
        const float inv = 1.0f / fmaxf((float)(e - s), 1.0f);
        float4 v = make_float4(ax * inv, ay * inv, az * inv, aw * inv);
        if (sbuf) {
            float4 sv = *(const float4*)(sbuf + (size_t)node * F + 4 * c4);
            v.x += sv.x; v.y += sv.y; v.z += sv.z; v.w += sv.w;
        }
        if (doRelu) {
            v.x = fmaxf(v.x, 0.f); v.y = fmaxf(v.y, 0.f);
            v.z = fmaxf(v.z, 0.f); v.w = fmaxf(v.w, 0.f);
        }
        float* orow = out + (size_t)node * ldout;
        *(float4*)(orow + 4 * c4) = v;
        if (hcopy) {
            float4 hv = *(const float4*)(hcopy + (size_t)node * F + 4 * c4);
            *(float4*)(orow + F + 4 * c4) = hv;
        }
    }
}

// ---------------- LDS-staged dual-OUTPUT GEMM: Y = A@Wn ; S = A@Ws + b -------
template<int K, int N>
__global__ __launch_bounds__(TB) void gemm_dualout_lds(
        const float* __restrict__ A, const float* __restrict__ Wn,
        const float* __restrict__ Ws, const float* __restrict__ bias,
        float* __restrict__ Y, float* __restrict__ S, int M) {
    constexpr int C = N / 8;
    constexpr int NC4 = C / 4;
    constexpr int KC0 = 2048 / N;
    constexpr int KC = KC0 < K ? KC0 : K;
    constexpr int P4 = (KC * N) / 1024;

    __shared__ float lwn[KC * N];
    __shared__ float lws[KC * N];

    const int tid = threadIdx.x;
    const int colg = tid & 7;
    const int rowg = tid >> 3;
    const int row0 = blockIdx.x * 64 + rowg * 2;
    const bool valid = row0 < M;
    const int c0 = colg * C;

    float4 accY[2][NC4], accS[2][NC4];
    #pragma unroll
    for (int r = 0; r < 2; ++r)
        #pragma unroll
        for (int j = 0; j < NC4; ++j) {
            accY[r][j] = make_float4(0.f, 0.f, 0.f, 0.f);
            accS[r][j] = make_float4(0.f, 0.f, 0.f, 0.f);
        }

    for (int kc = 0; kc < K; kc += KC) {
        __syncthreads();
        const float4* gwn = (const float4*)(Wn + (size_t)kc * N);
        const float4* gws = (const float4*)(Ws + (size_t)kc * N);
        #pragma unroll
        for (int i = 0; i < P4; ++i) {
            int f4i = tid + i * 256;
            ((float4*)lwn)[f4i] = gwn[f4i];
            ((float4*)lws)[f4i] = gws[f4i];
        }
        __syncthreads();
        if (valid) {
            const float* a = A + (size_t)row0 * K + kc;
            for (int k = 0; k < KC; k += 4) {
                float4 av[2];
                #pragma unroll
                for (int r = 0; r < 2; ++r)
                    av[r] = *(const float4*)(a + (size_t)r * K + k);
                #pragma unroll
                for (int kk = 0; kk < 4; ++kk) {
                    #pragma unroll
                    for (int j = 0; j < NC4; ++j) {
                        float4 wn = *(const float4*)(&lwn[(k + kk) * N + c0 + 4 * j]);
                        float4 ws = *(const float4*)(&lws[(k + kk) * N + c0 + 4 * j]);
                        #pragma unroll
                        for (int r = 0; r < 2; ++r) {
                            float ar = ((const float*)&av[r])[kk];
                            accY[r][j].x += ar * wn.x; accY[r][j].y += ar * wn.y;
                            accY[r][j].z += ar * wn.z; accY[r][j].w += ar * wn.w;
                            accS[r][j].x += ar * ws.x; accS[r][j].y += ar * ws.y;
                            accS[r][j].z += ar * ws.z; accS[r][j].w += ar * ws.w;
                        }
                    }
                }
            }
        }
    }

    if (valid) {
        #pragma unroll
        for (int j = 0; j < NC4; ++j) {
            const int c = c0 + 4 * j;
            float4 bb = *(const float4*)(bias + c);
            #pragma unroll
            for (int r = 0; r < 2; ++r) {
                const int row = row0 + r;
                *(float4*)(Y + (size_t)row * N + c) = accY[r][j];
                float4 v = accS[r][j];
                v.x += bb.x; v.y += bb.y; v.z += bb.z; v.w += bb.w;
                *(float4*)(S + (size_t)row * N + c) = v;
            }
        }
    }
}

// ---------------- LDS-staged dual-INPUT GEMM: out = relu(A@W + A2@W2 + b) ----
template<int K, int N>
__global__ __launch_bounds__(TB) void gemm_dualin_lds(
        const float* __restrict__ A, const float* __restrict__ W,
        const float* __restrict__ A2, const float* __restrict__ W2,
        const float* __restrict__ bias, float* __restrict__ out, int M) {
    constexpr int C = N / 8;
    constexpr int NC4 = C / 4;
    constexpr int KC0 = 2048 / N;
    constexpr int KC = KC0 < K ? KC0 : K;
    constexpr int P4 = (KC * N) / 1024;

    __shared__ float lw[KC * N];
    __shared__ float lw2[KC * N];

    const int tid = threadIdx.x;
    const int colg = tid & 7;
    const int rowg = tid >> 3;
    const int row0 = blockIdx.x * 64 + rowg * 2;
    const bool valid = row0 < M;
    const int c0 = colg * C;

    float4 acc[2][NC4];
    #pragma unroll
    for (int r = 0; r < 2; ++r)
        #pragma unroll
        for (int j = 0; j < NC4; ++j) acc[r][j] = make_float4(0.f, 0.f, 0.f, 0.f);

    for (int kc = 0; kc < K; kc += KC) {
        __syncthreads();
        const float4* gw  = (const float4*)(W  + (size_t)kc * N);
        const float4* gw2 = (const float4*)(W2 + (size_t)kc * N);
        #pragma unroll
        for (int i = 0; i < P4; ++i) {
            int f4i = tid + i * 256;
            ((float4*)lw)[f4i]  = gw[f4i];
            ((float4*)lw2)[f4i] = gw2[f4i];
        }
        __syncthreads();
        if (valid) {
            const float* a  = A  + (size_t)row0 * K + kc;
            const float* a2 = A2 + (size_t)row0 * K + kc;
            for (int k = 0; k < KC; k += 4) {
                float4 av[2], av2[2];
                #pragma unroll
                for (int r = 0; r < 2; ++r) {
                    av[r]  = *(const float4*)(a  + (size_t)r * K + k);
                    av2[r] = *(const float4*)(a2 + (size_t)r * K + k);
                }
                #pragma unroll
                for (int kk = 0; kk < 4; ++kk) {
                    #pragma unroll
                    for (int j = 0; j < NC4; ++j) {
                        float4 wv  = *(const float4*)(&lw[(k + kk) * N + c0 + 4 * j]);
                        float4 wv2 = *(const float4*)(&lw2[(k + kk) * N + c0 + 4 * j]);
                        #pragma unroll
                        for (int r = 0; r < 2; ++r) {
                            float ar  = ((const float*)&av[r])[kk];
                            float ar2 = ((const float*)&av2[r])[kk];
                            acc[r][j].x += ar * wv.x + ar2 * wv2.x;
                            acc[r][j].y += ar * wv.y + ar2 * wv2.y;
                            acc[r][j].z += ar * wv.z + ar2 * wv2.z;
                            acc[r][j].w += ar * wv.w + ar2 * wv2.w;
                        }
                    }
                }
            }
        }
    }

    if (valid) {
        #pragma unroll
        for (int j = 0; j < NC4; ++j) {
            const int c = c0 + 4 * j;
            float4 bb = *(const float4*)(bias + c);
            #pragma unroll
            for (int r = 0; r < 2; ++r) {
                float4 v = acc[r][j];
                v.x = fmaxf(v.x + bb.x, 0.f);
                v.y = fmaxf(v.y + bb.y, 0.f);
                v.z = fmaxf(v.z + bb.z, 0.f);
                v.w = fmaxf(v.w + bb.w, 0.f);
                *(float4*)(out + (size_t)(row0 + r) * N + c) = v;
            }
        }
    }
}

// ---------------- host orchestration ----------------------------------------
static inline int cdiv_i(long long a, int b) { return (int)((a + b - 1) / b); }

template<int F>
static void launch_gather(const float* x, const int* col, const int* rowptr,
                          const float* sbuf, const float* hcopy,
                          float* out, int M, int ldout, int relu, hipStream_t stream) {
    hipLaunchKernelGGL((gather_fused_kernel<F>), dim3(cdiv_i(M, TB / 64)), dim3(TB), 0, stream,
                       (const float4*)x, col, rowptr, sbuf, hcopy, out, M, ldout, relu);
}

extern "C" void kernel_launch(void* const* d_in, const int* in_sizes, int n_in,
                              void* d_out, int out_size, void* d_ws, size_t ws_size,
                              hipStream_t stream) {
    const float* in_feat = (const float*)d_in[0];
    const void* src = d_in[1];
    const void* dst = d_in[2];
    const float* Ws1 = (const float*)d_in[3];  const float* Wn1 = (const float*)d_in[4];  const float* b1 = (const float*)d_in[5];
    const float* Ws2 = (const float*)d_in[6];  const float* Wn2 = (const float*)d_in[7];  const float* b2 = (const float*)d_in[8];
    const float* Ws3 = (const float*)d_in[9];  const float* Wn3 = (const float*)d_in[10]; const float* b3 = (const float*)d_in[11];
    const float* Ws4 = (const float*)d_in[12]; const float* Wn4 = (const float*)d_in[13]; const float* b4 = (const float*)d_in[14];
    const float* Ws5 = (const float*)d_in[15]; const float* Wn5 = (const float*)d_in[16]; const float* b5 = (const float*)d_in[17];
    const float* Ws6 = (const float*)d_in[18]; const float* Wn6 = (const float*)d_in[19]; const float* b6 = (const float*)d_in[20];

    const int M  = in_sizes[0] / 64;   // 100000 nodes
    const int nE = in_sizes[1];        // 1600000 edges
    const int nB = cdiv_i(M, CHUNK);   // scan chunks (49)

    // workspace layout
    float* ws   = (float*)d_ws;
    float* P1   = ws;                        // M*128  (h1, later h5)
    float* P2   = P1 + (size_t)M * 128;      // M*64   (h2, later h4)
    float* P3   = P2 + (size_t)M * 64;       // M*32   (h3)
    float* ybuf = P3 + (size_t)M * 32;       // M*64   (transformed features to aggregate)
    float* sbuf = ybuf + (size_t)M * 64;     // M*64   (self part + bias)
    int* deg    = (int*)(sbuf + (size_t)M * 64);  // M ints (histogram)
    int* cursor = deg + M;                   // M ints
    int* rowptr = cursor + M;                // M+1 ints
    int* col    = rowptr + (M + 1);          // nE ints
    int* flag   = col + nE;                  // 1 int
    int* bsum   = flag + 1;                  // nB ints
    int* boff   = bsum + nB;                 // nB ints

    // ---- CSR build
    hipLaunchKernelGGL(detect_idx_kernel, dim3(1), dim3(TB), 0, stream,
                       (const int*)src, (const int*)dst, nE, flag);
    hipMemsetAsync(deg, 0, (size_t)M * sizeof(int), stream);
    hipLaunchKernelGGL(hist_kernel, dim3(cdiv_i(nE, TB)), dim3(TB), 0, stream,
                       dst, flag, deg, nE);
    hipLaunchKernelGGL(bsum_kernel, dim3(nB), dim3(TB), 0, stream, deg, bsum, M);
    hipLaunchKernelGGL(topscan_kernel, dim3(1), dim3(64), 0, stream,
                       bsum, boff, rowptr, nB, M);
    hipLaunchKernelGGL(scan_chunk_kernel, dim3(nB), dim3(TB), 0, stream,
                       deg, boff, rowptr, cursor, M);
    hipLaunchKernelGGL(fill_kernel, dim3(cdiv_i(nE, TB)), dim3(TB), 0, stream,
                       src, dst, flag, cursor, col, nE);

    const int gblocks = cdiv_i(M, 64);

    // ---- layer 1: 64 -> 128, relu.  ybuf = mean_nbr(in_feat); dual-input GEMM
    launch_gather<64>(in_feat, col, rowptr, nullptr, nullptr, ybuf, M, 64, 0, stream);
    hipLaunchKernelGGL((gemm_dualin_lds<64, 128>), dim3(gblocks), dim3(TB), 0, stream,
                       in_feat, Ws1, ybuf, Wn1, b1, P1, M);

    // ---- layer 2: 128 -> 64, relu
    hipLaunchKernelGGL((gemm_dualout_lds<128, 64>), dim3(gblocks), dim3(TB), 0, stream,
                       P1, Wn2, Ws2, b2, ybuf, sbuf, M);
    launch_gather<64>(ybuf, col, rowptr, sbuf, nullptr, P2, M, 64, 1, stream);

    // ---- layer 3: 64 -> 32, relu
    hipLaunchKernelGGL((gemm_dualout_lds<64, 32>), dim3(gblocks), dim3(TB), 0, stream,
                       P2, Wn3, Ws3, b3, ybuf, sbuf, M);
    launch_gather<32>(ybuf, col, rowptr, sbuf, nullptr, P3, M, 32, 1, stream);

    // ---- layer 4: 32 -> 32, relu, concat h3 -> h4 (64 wide) in P2
    hipLaunchKernelGGL((gemm_dualout_lds<32, 32>), dim3(gblocks), dim3(TB), 0, stream,
                       P3, Wn4, Ws4, b4, ybuf, sbuf, M);
    launch_gather<32>(ybuf, col, rowptr, sbuf, P3, P2, M, 64, 1, stream);

    // ---- layer 5: 64 -> 64, relu, concat h4 -> h5 (128 wide) in P1
    hipLaunchKernelGGL((gemm_dualout_lds<64, 64>), dim3(gblocks), dim3(TB), 0, stream,
                       P2, Wn5, Ws5, b5, ybuf, sbuf, M);
    launch_gather<64>(ybuf, col, rowptr, sbuf, P2, P1, M, 128, 1, stream);

    // ---- layer 6: 128 -> 64, no relu, to d_out
    hipLaunchKernelGGL((gemm_dualout_lds<128, 64>), dim3(gblocks), dim3(TB), 0, stream,
                       P1, Wn6, Ws6, b6, ybuf, sbuf, M);
    launch_gather<64>(ybuf, col, rowptr, sbuf, nullptr, (float*)d_out, M, 64, 0, stream);
}